// Round 2
// baseline (286.272 us; speedup 1.0000x reference)
//
#include <hip/hip_runtime.h>
#include <math.h>

#define BB 4
#define CC 256
#define HH 512
#define WW 256
#define CRED 64
#define GIN 4
#define KNN8 8

// ---------- helpers ----------
__device__ __forceinline__ float wave_sum(float v) {
#pragma unroll
    for (int off = 32; off; off >>= 1) v += __shfl_xor(v, off, 64);
    return v;
}

// ---------- kernel 1: fused mean over W + grouped reduce ----------
// one wave per (b, o, h); XrT layout [B][CRED][H]
__global__ __launch_bounds__(256) void mean_reduce_kernel(const float* __restrict__ x,
                                                          const float* __restrict__ Wr,
                                                          float* __restrict__ XrT) {
    int gid  = blockIdx.x * 256 + threadIdx.x;
    int wid  = gid >> 6;          // over B*64*H = 131072
    int lane = threadIdx.x & 63;
    int h = wid & 511;
    int o = (wid >> 9) & 63;
    int b = wid >> 15;
    float s = 0.f;
#pragma unroll
    for (int g = 0; g < GIN; ++g) {
        const float4 v = *(const float4*)(x + ((size_t)((b * CC + o * GIN + g) * HH + h)) * WW + lane * 4);
        s += Wr[o * GIN + g] * (v.x + v.y + v.z + v.w);
    }
    s = wave_sum(s);
    if (lane == 0) XrT[((b * CRED + o) << 9) + h] = s * (1.f / 256.f);
}

// ---------- kernel 2: normalize Uk rows ----------
// one wave per (b,h) row of 64
__global__ __launch_bounds__(256) void normalize_kernel(const float* __restrict__ Uk,
                                                        float* __restrict__ Un) {
    int gid  = blockIdx.x * 256 + threadIdx.x;
    int wid  = gid >> 6;          // over B*H = 2048
    int lane = threadIdx.x & 63;
    float v  = Uk[wid * 64 + lane];
    float ss = wave_sum(v * v);
    float norm = fmaxf(sqrtf(ss), 1e-12f);
    Un[wid * 64 + lane] = v / norm;
}

// ---------- kernel 3: cosine sim + stable top-8 + degree ----------
// one wave per (b,h); lane owns candidates g = lane + 64*j
__global__ __launch_bounds__(256) void topk_kernel(const float* __restrict__ Un,
                                                   float* __restrict__ topv,
                                                   int* __restrict__ topi,
                                                   float* __restrict__ deg) {
    int gid  = blockIdx.x * 256 + threadIdx.x;
    int wid  = gid >> 6;          // over B*H = 2048
    int lane = threadIdx.x & 63;
    int b = wid >> 9;
    const float* Ub = Un + b * HH * 64;
    const float* uh = Un + wid * 64;

    float sim[8];
#pragma unroll
    for (int j = 0; j < 8; ++j) sim[j] = 0.f;
#pragma unroll 4
    for (int kk = 0; kk < 64; ++kk) {
        float uhv = uh[kk];
#pragma unroll
        for (int j = 0; j < 8; ++j) sim[j] += uhv * Ub[(lane + 64 * j) * 64 + kk];
    }

    float vsum = 0.f;
#pragma unroll
    for (int r = 0; r < KNN8; ++r) {
        // lane-local argmax, strictly-greater keeps smallest j (== smallest g) on ties
        float bv = sim[0]; int bj = 0;
#pragma unroll
        for (int j = 1; j < 8; ++j) { if (sim[j] > bv) { bv = sim[j]; bj = j; } }
        float v = bv; int g = lane + 64 * bj;
        // cross-lane argmax: larger value wins; equal value -> smaller index
#pragma unroll
        for (int off = 32; off; off >>= 1) {
            float ov = __shfl_xor(v, off, 64);
            int   og = __shfl_xor(g, off, 64);
            if (ov > v || (ov == v && og < g)) { v = ov; g = og; }
        }
        vsum += v;
        if (lane == 0) { topv[wid * KNN8 + r] = v; topi[wid * KNN8 + r] = g; }
        if ((g & 63) == lane) sim[g >> 6] = -INFINITY;   // owner removes winner
    }
    if (lane == 0) deg[wid] = vsum;
}

// ---------- kernel 4: support = Xr @ W_gcn ----------
// one wave per (b,h); lane = d
__global__ __launch_bounds__(256) void support_kernel(const float* __restrict__ XrT,
                                                      const float* __restrict__ Wg,
                                                      float* __restrict__ support) {
    int gid  = blockIdx.x * 256 + threadIdx.x;
    int wid  = gid >> 6;          // over B*H
    int d    = threadIdx.x & 63;
    int b = wid >> 9, h = wid & 511;
    const float* xr = XrT + b * CRED * HH;
    float s = 0.f;
#pragma unroll 8
    for (int c = 0; c < CRED; ++c) s += xr[c * HH + h] * Wg[c * CRED + d];
    support[wid * CRED + d] = s;
}

// ---------- kernel 5: GCN aggregate + bias + relu ----------
// one wave per (b,h); lane = output channel g
__global__ __launch_bounds__(256) void gcn_kernel(const float* __restrict__ support,
                                                  const float* __restrict__ topv,
                                                  const int* __restrict__ topi,
                                                  const float* __restrict__ deg,
                                                  const float* __restrict__ bg,
                                                  float* __restrict__ gcn) {
    int gid  = blockIdx.x * 256 + threadIdx.x;
    int wid  = gid >> 6;          // over B*H
    int lane = threadIdx.x & 63;
    int b = wid >> 9;
    float dh = 1.0f / sqrtf(deg[wid]);
    const float* sb = support + b * HH * CRED;
    float acc = 0.f;
#pragma unroll
    for (int k = 0; k < KNN8; ++k) {
        int   i = topi[wid * KNN8 + k];
        float w = topv[wid * KNN8 + k] * dh * (1.0f / sqrtf(deg[b * HH + i]));
        acc += w * sb[i * CRED + lane];
    }
    acc += bg[lane];
    gcn[wid * CRED + lane] = fmaxf(acc, 0.f);
}

// ---------- kernel 6: expand + broadcast over W ----------
// one wave per (b,c,h) output row; 64 lanes x float4
__global__ __launch_bounds__(256) void out_kernel(const float* __restrict__ gcn,
                                                  const float* __restrict__ We,
                                                  float* __restrict__ out) {
    int gid = blockIdx.x * 256 + threadIdx.x;   // over B*C*H*64
    int row = gid >> 6;                         // (b*C + c)*H + h
    int w4  = gid & 63;
    int h = row & 511;
    int c = (row >> 9) & 255;
    int b = row >> 17;
    float val = gcn[(((b << 9) + h) << 6) + (c >> 2)] * We[c];  // We flat index g*4+j == c
    float4 v = make_float4(val, val, val, val);
    *(float4*)(out + (size_t)row * WW + w4 * 4) = v;
}

extern "C" void kernel_launch(void* const* d_in, const int* in_sizes, int n_in,
                              void* d_out, int out_size, void* d_ws, size_t ws_size,
                              hipStream_t stream) {
    const float* x  = (const float*)d_in[0];
    const float* Uk = (const float*)d_in[1];
    const float* Wr = (const float*)d_in[2];
    const float* Wg = (const float*)d_in[3];
    const float* bg = (const float*)d_in[4];
    const float* We = (const float*)d_in[5];
    float* out = (float*)d_out;
    float* ws  = (float*)d_ws;

    float* XrT  = ws;                 // B*64*H         = 131072
    float* Un   = ws + 131072;        // B*H*64         = 131072
    float* topv = ws + 262144;        // B*H*8          = 16384
    int*   topi = (int*)(ws + 278528);// B*H*8          = 16384
    float* deg  = ws + 294912;        // B*H            = 2048
    float* sup  = ws + 296960;        // B*H*64         = 131072
    float* gcn  = ws + 428032;        // B*H*64         = 131072

    hipLaunchKernelGGL(mean_reduce_kernel, dim3(32768), dim3(256), 0, stream, x, Wr, XrT);
    hipLaunchKernelGGL(normalize_kernel,   dim3(512),   dim3(256), 0, stream, Uk, Un);
    hipLaunchKernelGGL(topk_kernel,        dim3(512),   dim3(256), 0, stream, Un, topv, topi, deg);
    hipLaunchKernelGGL(support_kernel,     dim3(512),   dim3(256), 0, stream, XrT, Wg, sup);
    hipLaunchKernelGGL(gcn_kernel,         dim3(512),   dim3(256), 0, stream, sup, topv, topi, deg, bg, gcn);
    hipLaunchKernelGGL(out_kernel,         dim3(131072),dim3(256), 0, stream, gcn, We, out);
}